// Round 3
// baseline (460.677 us; speedup 1.0000x reference)
//
#include <hip/hip_runtime.h>

// ---------------------------------------------------------------------------
// OseroNetworks, round 5: pinned up-front loads to break latency serialization.
//
// Rounds 2-4 (three different structures) all plateau at 150-165us with
// VALUBusy<=31%, HBM<=23%, i.e. latency-bound. Round 3 ran at VGPR_Count=28:
// its 13 independent VMEM loads need ~29 dest VGPRs to be in flight at once,
// so the compiler emitted serialized load->wait->consume->load rounds (~4 per
// wave, ~900cy each). That serialization is the invariant bottleneck.
//
// This version:
//  * slice-per-thread (4 threads/element), 13 VMEM loads per thread issued
//    up-front and PINNED with sched_barrier(0) -- no sinking into chains.
//    One latency exposure per wave instead of four.
//  * loads issued BEFORE weight staging + __syncthreads, hiding HBM latency
//    under the staging phase.
//  * weights pre-paired in LDS (round 4 path: broadcast ds_read, in-order
//    returns, zero bank conflicts measured).
//  * __launch_bounds__(256,6): VGPR cap 80 -- room for in-flight loads, no
//    spill, 6 waves/SIMD.
//  * all scalar tail terms (b3's, cn*nW+nb) folded into the lane-0 store.
// ---------------------------------------------------------------------------

typedef float f2 __attribute__((ext_vector_type(2)));

__device__ __forceinline__ f2 pk_fma(f2 a, f2 b, f2 c) {
    return __builtin_elementwise_fma(a, b, c);
}

// Pair-packers for staging: wp[op*D+i] = {W[2op][i], W[2op+1][i]}.
__device__ __forceinline__ f2 pr10(const float* __restrict__ W, int j) {
    const int op = j / 10, i = j - op * 10;
    return (f2){W[op * 20 + i], W[op * 20 + 10 + i]};
}
__device__ __forceinline__ f2 pr8(const float* __restrict__ W, int j) {
    const int op = j >> 3, i = j & 7;
    return (f2){W[op * 16 + i], W[op * 16 + 8 + i]};
}
__device__ __forceinline__ f2 prc(const float* __restrict__ p, int k) {
    return (f2){p[2 * k], p[2 * k + 1]};
}

struct SW {
    f2 eW1[50], eW2[50], cW1[50], cW2[50];   // 10-D layers, paired outputs
    f2 xW1[32], xW2[32];                     // 8-D layers, paired outputs
    f2 eW3[5], cW3[5], xW3[4];               // output rows, paired
    f2 eb1[5], eb2[5], cb1[5], cb2[5];       // biases, paired
    f2 xb1[4], xb2[4];
};

// 3-layer MLP over one D-vector in registers; weights from LDS (broadcast).
// Returns the un-biased output (b3 folded in by caller).
template<int D>
__device__ __forceinline__ float mlp_slice(const f2* xs,
                                           const f2* w1p, const f2* b1p,
                                           const f2* w2p, const f2* b2p,
                                           const f2* w3p)
{
    constexpr int H = D / 2;

    f2 h1[H];
    #pragma unroll
    for (int op = 0; op < H; ++op) {
        f2 a = b1p[op];
        #pragma unroll
        for (int i = 0; i < D; ++i) {
            const float xv = (i & 1) ? xs[i >> 1].y : xs[i >> 1].x;
            a = pk_fma(w1p[op * D + i], (f2){xv, xv}, a);
        }
        h1[op] = __builtin_elementwise_max(a, (f2){0.0f, 0.0f});
    }

    f2 h2[H];
    #pragma unroll
    for (int op = 0; op < H; ++op) {
        f2 a = b2p[op];
        #pragma unroll
        for (int i = 0; i < D; ++i) {
            const float hv = (i & 1) ? h1[i >> 1].y : h1[i >> 1].x;
            a = pk_fma(w2p[op * D + i], (f2){hv, hv}, a);
        }
        h2[op] = __builtin_elementwise_max(a, (f2){0.0f, 0.0f});
    }

    f2 o = {0.0f, 0.0f};
    #pragma unroll
    for (int k = 0; k < H; ++k)
        o = pk_fma(w3p[k], h2[k], o);
    return o.x + o.y;
}

__global__ __launch_bounds__(256, 6)
void osero_kernel(const float* __restrict__ edge,
                  const float* __restrict__ cross_,
                  const float* __restrict__ corner,
                  const float* __restrict__ cn,
                  const float* __restrict__ eW1, const float* __restrict__ eb1,
                  const float* __restrict__ eW2, const float* __restrict__ eb2,
                  const float* __restrict__ eW3, const float* __restrict__ eb3,
                  const float* __restrict__ xW1, const float* __restrict__ xb1,
                  const float* __restrict__ xW2, const float* __restrict__ xb2,
                  const float* __restrict__ xW3, const float* __restrict__ xb3,
                  const float* __restrict__ cW1, const float* __restrict__ cb1,
                  const float* __restrict__ cW2, const float* __restrict__ cb2,
                  const float* __restrict__ cW3, const float* __restrict__ cb3,
                  const float* __restrict__ nW,  const float* __restrict__ nb,
                  float* __restrict__ out, int nthr)
{
    __shared__ SW sw;
    const int t = threadIdx.x;
    const int g0 = blockIdx.x * 256 + t;            // slice-thread id
    const int g  = (g0 < nthr) ? g0 : 0;            // clamp (grid is exact for B%64==0)
    const int e  = g >> 2;
    const int s  = g & 3;

    // ---- phase 1: issue ALL per-thread data loads (13 VMEM), pinned -------
    f2 xe[5], xq[5], xc[4];
    {
        const f2* pe = reinterpret_cast<const f2*>(edge)   + (size_t)g * 5;
        const f2* pq = reinterpret_cast<const f2*>(corner) + (size_t)g * 5;
        #pragma unroll
        for (int k = 0; k < 5; ++k) xe[k] = pe[k];
        #pragma unroll
        for (int k = 0; k < 5; ++k) xq[k] = pq[k];
        const float4* pc = reinterpret_cast<const float4*>(cross_) + (size_t)g * 2;
        const float4 v0 = pc[0];
        const float4 v1 = pc[1];
        xc[0] = (f2){v0.x, v0.y}; xc[1] = (f2){v0.z, v0.w};
        xc[2] = (f2){v1.x, v1.y}; xc[3] = (f2){v1.z, v1.w};
    }
    const float cnv = (s == 0) ? cn[e] : 0.0f;
    __builtin_amdgcn_sched_barrier(0);   // loads stay issued above this point

    // ---- phase 2: stage paired weights into LDS (hides load latency) ------
    if (t < 50) {
        sw.eW1[t] = pr10(eW1, t); sw.eW2[t] = pr10(eW2, t);
        sw.cW1[t] = pr10(cW1, t); sw.cW2[t] = pr10(cW2, t);
    } else if (t >= 64 && t < 96) {
        const int j = t - 64;
        sw.xW1[j] = pr8(xW1, j); sw.xW2[j] = pr8(xW2, j);
    } else if (t >= 128 && t < 133) {
        const int k = t - 128;
        sw.eW3[k] = prc(eW3, k); sw.cW3[k] = prc(cW3, k);
        sw.eb1[k] = prc(eb1, k); sw.eb2[k] = prc(eb2, k);
        sw.cb1[k] = prc(cb1, k); sw.cb2[k] = prc(cb2, k);
    } else if (t >= 192 && t < 196) {
        const int k = t - 192;
        sw.xW3[k] = prc(xW3, k);
        sw.xb1[k] = prc(xb1, k); sw.xb2[k] = prc(xb2, k);
    }
    __syncthreads();

    // ---- phase 3: compute (weights broadcast from LDS) --------------------
    float val = mlp_slice<10>(xe, sw.eW1, sw.eb1, sw.eW2, sw.eb2, sw.eW3);
    val      += mlp_slice<10>(xq, sw.cW1, sw.cb1, sw.cW2, sw.cb2, sw.cW3);
    val      += mlp_slice<8> (xc, sw.xW1, sw.xb1, sw.xW2, sw.xb2, sw.xW3);

    // ---- phase 4: width-4 butterfly, single store per element -------------
    val += __shfl_xor(val, 1, 4);
    val += __shfl_xor(val, 2, 4);

    if (s == 0 && g0 < nthr) {
        // 4 slices each contributed one b3; cn-term folded here too.
        const float tail = 4.0f * (eb3[0] + cb3[0] + xb3[0])
                         + fmaf(cnv, nW[0], nb[0]);
        out[e] = val + tail;
    }
}

extern "C" void kernel_launch(void* const* d_in, const int* in_sizes, int n_in,
                              void* d_out, int out_size, void* d_ws, size_t ws_size,
                              hipStream_t stream) {
    const float* edge   = (const float*)d_in[0];
    const float* cross_ = (const float*)d_in[1];
    const float* corner = (const float*)d_in[2];
    const float* cn     = (const float*)d_in[3];
    const float* eW1 = (const float*)d_in[4];
    const float* eb1 = (const float*)d_in[5];
    const float* eW2 = (const float*)d_in[6];
    const float* eb2 = (const float*)d_in[7];
    const float* eW3 = (const float*)d_in[8];
    const float* eb3 = (const float*)d_in[9];
    const float* xW1 = (const float*)d_in[10];
    const float* xb1 = (const float*)d_in[11];
    const float* xW2 = (const float*)d_in[12];
    const float* xb2 = (const float*)d_in[13];
    const float* xW3 = (const float*)d_in[14];
    const float* xb3 = (const float*)d_in[15];
    const float* cW1 = (const float*)d_in[16];
    const float* cb1 = (const float*)d_in[17];
    const float* cW2 = (const float*)d_in[18];
    const float* cb2 = (const float*)d_in[19];
    const float* cW3 = (const float*)d_in[20];
    const float* cb3 = (const float*)d_in[21];
    const float* nW  = (const float*)d_in[22];
    const float* nb  = (const float*)d_in[23];

    const int nelem = in_sizes[3];          // cn is [B,1] -> B
    const int nthr  = nelem * 4;            // one thread per (element, slice)
    const int nblk  = (nthr + 255) / 256;

    osero_kernel<<<dim3(nblk), 256, 0, stream>>>(edge, cross_, corner, cn,
                                                 eW1, eb1, eW2, eb2, eW3, eb3,
                                                 xW1, xb1, xW2, xb2, xW3, xb3,
                                                 cW1, cb1, cW2, cb2, cW3, cb3,
                                                 nW, nb, (float*)d_out, nthr);
}